// Round 5
// baseline (2182.345 us; speedup 1.0000x reference)
//
#include <hip/hip_runtime.h>
#include <math.h>

#define NH 16
#define HD 64
#define DIM 1024
#define QKV_DIM 3072
#define MAXLEN 2048

// hardcoded problem constants (fixed by reference setup)
__device__ __constant__ int g_cu[5]  = {0, 2048, 3584, 4608, 5120};
__device__ __constant__ int g_seq[4] = {2048, 1536, 1024, 512};

// ---------------------------------------------------------------------------
// GEMM: C[M][N] = A[M][K] * B[N][K]^T   (both A,B row-major, K-contiguous)
// 128x128 tile, BK=16, 256 threads, 8x8 per thread, fp32.
// ---------------------------------------------------------------------------
__global__ __launch_bounds__(256) void gemm_abt(const float* __restrict__ A,
                                                const float* __restrict__ B,
                                                float* __restrict__ C,
                                                int M, int N, int K) {
    constexpr int BM = 128, BN = 128, BK = 16;
    __shared__ float As[BK][BM + 4];
    __shared__ float Bs[BK][BN + 4];

    const int tid = threadIdx.x;
    const int bm = blockIdx.y * BM;
    const int bn = blockIdx.x * BN;
    const int ty = tid / 16;
    const int tx = tid % 16;

    float acc[8][8] = {};

    for (int k0 = 0; k0 < K; k0 += BK) {
#pragma unroll
        for (int it = 0; it < 2; ++it) {
            int item = tid + it * 256;
            int r = item >> 2;
            int c4 = item & 3;
            float4 v = *(const float4*)&A[(size_t)(bm + r) * K + k0 + c4 * 4];
            As[c4 * 4 + 0][r] = v.x;
            As[c4 * 4 + 1][r] = v.y;
            As[c4 * 4 + 2][r] = v.z;
            As[c4 * 4 + 3][r] = v.w;
        }
#pragma unroll
        for (int it = 0; it < 2; ++it) {
            int item = tid + it * 256;
            int r = item >> 2;
            int c4 = item & 3;
            float4 v = *(const float4*)&B[(size_t)(bn + r) * K + k0 + c4 * 4];
            Bs[c4 * 4 + 0][r] = v.x;
            Bs[c4 * 4 + 1][r] = v.y;
            Bs[c4 * 4 + 2][r] = v.z;
            Bs[c4 * 4 + 3][r] = v.w;
        }
        __syncthreads();

#pragma unroll
        for (int k = 0; k < BK; ++k) {
            float a[8], b[8];
            *(float4*)&a[0] = *(const float4*)&As[k][ty * 8 + 0];
            *(float4*)&a[4] = *(const float4*)&As[k][ty * 8 + 4];
            *(float4*)&b[0] = *(const float4*)&Bs[k][tx * 8 + 0];
            *(float4*)&b[4] = *(const float4*)&Bs[k][tx * 8 + 4];
#pragma unroll
            for (int i = 0; i < 8; ++i)
#pragma unroll
                for (int j = 0; j < 8; ++j) acc[i][j] = fmaf(a[i], b[j], acc[i][j]);
        }
        __syncthreads();
    }

#pragma unroll
    for (int i = 0; i < 8; ++i) {
#pragma unroll
        for (int j = 0; j < 8; j += 4) {
            float4 v = {acc[i][j], acc[i][j + 1], acc[i][j + 2], acc[i][j + 3]};
            *(float4*)&C[(size_t)(bm + ty * 8 + i) * N + bn + tx * 8 + j] = v;
        }
    }
}

// ---------------------------------------------------------------------------
// RoPE in place on q and k halves of the unpadded qkv buffer.
// ---------------------------------------------------------------------------
__global__ __launch_bounds__(256) void rope_kernel(float* __restrict__ qkv, int total) {
    int id = blockIdx.x * blockDim.x + threadIdx.x;
    int nitems = total * NH * 32;
    if (id >= nitems) return;
    int j = id & 31;
    int h = (id >> 5) & (NH - 1);
    int row = id >> 9;

    int b = 0;
    while (row >= g_cu[b + 1]) b++;
    int pos = row - g_cu[b];

    float inv_freq = powf(10000.0f, -(float)(2 * j) / 64.0f);
    float fr = (float)pos * inv_freq;
    float c = cosf(fr), s = sinf(fr);

    float* base = qkv + (size_t)row * QKV_DIM + h * HD;
#pragma unroll
    for (int part = 0; part < 2; ++part) {
        float* p = base + part * DIM;
        float x1 = p[j];
        float x2 = p[j + 32];
        p[j] = x1 * c - x2 * s;
        p[j + 32] = x2 * c + x1 * s;
    }
}

// ---------------------------------------------------------------------------
// Attention v3: 4 lanes per query row (quad owns 16 dims), but now each lane
// handles TWO rows (r0, r0+32) so every K/V float4 pulled from LDS feeds 2x
// the FMAs (v2 was LDS-throughput-bound at 40% VALUBusy). QK dot uses 4
// partial accumulators per row (chain depth 4 instead of 16). Softmax runs in
// exp2 domain (log2e folded into q scale) so exp is a bare v_exp_f32.
// Key tile = 64 (half the syncs of v2), scores chunked by 16 to bound regs.
// Block = 128 threads = 64 query rows of one (batch, head).
// Padded keys (score 0, v 0) contribute (MAXLEN-L)*2^(-m) to the denom only.
// ---------------------------------------------------------------------------
__global__ __launch_bounds__(128, 2) void attn_kernel(const float* __restrict__ qkv,
                                                      float* __restrict__ attn) {
    __shared__ float Ks[64][64];
    __shared__ float Vs[64][64];

    // blockIdx.x in [0,80): per-batch 64-row tile counts {32,24,16,8}.
    const int tiles_pref[5] = {0, 32, 56, 72, 80};
    int t = blockIdx.x;
    int b = 0;
    while (t >= tiles_pref[b + 1]) b++;
    const int qstart = (t - tiles_pref[b]) * 64;
    const int h = blockIdx.y;
    const int L = g_seq[b];
    const int base = g_cu[b];
    const int tid = threadIdx.x;
    const int r0 = tid >> 2;    // 0..31; lane handles rows r0 and r0+32
    const int quad = tid & 3;   // 16-dim quarter owned by this lane

    const float scale = 0.125f * 1.44269504088896f;  // 1/sqrt(64) * log2(e)
    const float* qr0 = qkv + (size_t)(base + qstart + r0) * QKV_DIM + h * HD + quad * 16;
    const float* qr1 = qr0 + (size_t)32 * QKV_DIM;
    float q0[16], q1[16];
#pragma unroll
    for (int i = 0; i < 4; ++i) {
        float4 v = *(const float4*)&qr0[i * 4];
        q0[i * 4 + 0] = v.x * scale; q0[i * 4 + 1] = v.y * scale;
        q0[i * 4 + 2] = v.z * scale; q0[i * 4 + 3] = v.w * scale;
        float4 w = *(const float4*)&qr1[i * 4];
        q1[i * 4 + 0] = w.x * scale; q1[i * 4 + 1] = w.y * scale;
        q1[i * 4 + 2] = w.z * scale; q1[i * 4 + 3] = w.w * scale;
    }

    float acc0[16] = {}, acc1[16] = {};
    float m0 = -1e30f, m1 = -1e30f, d0 = 0.0f, d1 = 0.0f;

    for (int k0 = 0; k0 < L; k0 += 64) {
        // stage 64x64 K and V tiles: 1024 float4 each, 8 per thread each
#pragma unroll
        for (int it = 0; it < 8; ++it) {
            int item = tid + it * 128;
            int r = item >> 4;       // 0..63
            int c4 = item & 15;      // 0..15
            const float* src = qkv + (size_t)(base + k0 + r) * QKV_DIM + DIM + h * HD + c4 * 4;
            *(float4*)&Ks[r][c4 * 4] = *(const float4*)src;
            *(float4*)&Vs[r][c4 * 4] = *(const float4*)(src + DIM);
        }
        __syncthreads();

        for (int c = 0; c < 64; c += 16) {
            float s0[16], s1[16];
            float tmax0 = -1e30f, tmax1 = -1e30f;
#pragma unroll
            for (int kk = 0; kk < 16; ++kk) {
                const float* kr = &Ks[c + kk][quad * 16];
                float p0[4] = {}, p1[4] = {};
#pragma unroll
                for (int i = 0; i < 4; ++i) {
                    float4 kv = *(const float4*)&kr[i * 4];
                    p0[i] = fmaf(q0[i * 4 + 0], kv.x, p0[i]);
                    p0[i] = fmaf(q0[i * 4 + 1], kv.y, p0[i]);
                    p0[i] = fmaf(q0[i * 4 + 2], kv.z, p0[i]);
                    p0[i] = fmaf(q0[i * 4 + 3], kv.w, p0[i]);
                    p1[i] = fmaf(q1[i * 4 + 0], kv.x, p1[i]);
                    p1[i] = fmaf(q1[i * 4 + 1], kv.y, p1[i]);
                    p1[i] = fmaf(q1[i * 4 + 2], kv.z, p1[i]);
                    p1[i] = fmaf(q1[i * 4 + 3], kv.w, p1[i]);
                }
                float dot0 = (p0[0] + p0[1]) + (p0[2] + p0[3]);
                float dot1 = (p1[0] + p1[1]) + (p1[2] + p1[3]);
                dot0 += __shfl_xor(dot0, 1);
                dot0 += __shfl_xor(dot0, 2);
                dot1 += __shfl_xor(dot1, 1);
                dot1 += __shfl_xor(dot1, 2);
                s0[kk] = dot0; tmax0 = fmaxf(tmax0, dot0);
                s1[kk] = dot1; tmax1 = fmaxf(tmax1, dot1);
            }

            float mn0 = fmaxf(m0, tmax0);
            float cr0 = exp2f(m0 - mn0);
            d0 *= cr0; m0 = mn0;
            float mn1 = fmaxf(m1, tmax1);
            float cr1 = exp2f(m1 - mn1);
            d1 *= cr1; m1 = mn1;
#pragma unroll
            for (int i = 0; i < 16; ++i) { acc0[i] *= cr0; acc1[i] *= cr1; }

#pragma unroll
            for (int kk = 0; kk < 16; ++kk) {
                float p0 = exp2f(s0[kk] - m0); d0 += p0;
                float p1 = exp2f(s1[kk] - m1); d1 += p1;
                const float* vr = &Vs[c + kk][quad * 16];
#pragma unroll
                for (int i = 0; i < 4; ++i) {
                    float4 vv = *(const float4*)&vr[i * 4];
                    acc0[i * 4 + 0] = fmaf(p0, vv.x, acc0[i * 4 + 0]);
                    acc0[i * 4 + 1] = fmaf(p0, vv.y, acc0[i * 4 + 1]);
                    acc0[i * 4 + 2] = fmaf(p0, vv.z, acc0[i * 4 + 2]);
                    acc0[i * 4 + 3] = fmaf(p0, vv.w, acc0[i * 4 + 3]);
                    acc1[i * 4 + 0] = fmaf(p1, vv.x, acc1[i * 4 + 0]);
                    acc1[i * 4 + 1] = fmaf(p1, vv.y, acc1[i * 4 + 1]);
                    acc1[i * 4 + 2] = fmaf(p1, vv.z, acc1[i * 4 + 2]);
                    acc1[i * 4 + 3] = fmaf(p1, vv.w, acc1[i * 4 + 3]);
                }
            }
        }
        __syncthreads();
    }

    // padded keys: score 0 (also 0 in exp2-scaled domain), v 0 -> denom only
    int npad = MAXLEN - L;
    if (npad) {
        float pad = (float)npad;
        d0 += pad * exp2f(0.0f - m0);
        d1 += pad * exp2f(0.0f - m1);
    }

    float inv0 = 1.0f / d0;
    float inv1 = 1.0f / d1;
    float* orow0 = attn + (size_t)(base + qstart + r0) * DIM + h * HD + quad * 16;
    float* orow1 = orow0 + (size_t)32 * DIM;
#pragma unroll
    for (int i = 0; i < 4; ++i) {
        float4 v0 = {acc0[i * 4 + 0] * inv0, acc0[i * 4 + 1] * inv0,
                     acc0[i * 4 + 2] * inv0, acc0[i * 4 + 3] * inv0};
        *(float4*)&orow0[i * 4] = v0;
        float4 v1 = {acc1[i * 4 + 0] * inv1, acc1[i * 4 + 1] * inv1,
                     acc1[i * 4 + 2] * inv1, acc1[i * 4 + 3] * inv1};
        *(float4*)&orow1[i * 4] = v1;
    }
}

// ---------------------------------------------------------------------------
extern "C" void kernel_launch(void* const* d_in, const int* in_sizes, int n_in,
                              void* d_out, int out_size, void* d_ws, size_t ws_size,
                              hipStream_t stream) {
    const float* hidden = (const float*)d_in[0];
    const float* Wqkv = (const float*)d_in[1];
    const float* Wo = (const float*)d_in[2];
    float* out = (float*)d_out;

    const int total = in_sizes[0] / DIM;  // 5120

    float* qkv = (float*)d_ws;                        // total * 3072
    float* attn = qkv + (size_t)total * QKV_DIM;      // total * 1024

    // 1) qkv = hidden @ Wqkv^T   (5120 x 3072, K=1024)
    gemm_abt<<<dim3(QKV_DIM / 128, total / 128), 256, 0, stream>>>(
        hidden, Wqkv, qkv, total, QKV_DIM, DIM);

    // 2) RoPE in place on q,k
    int nitems = total * NH * 32;
    rope_kernel<<<(nitems + 255) / 256, 256, 0, stream>>>(qkv, total);

    // 3) attention -> attn buffer
    attn_kernel<<<dim3(80, NH), 128, 0, stream>>>(qkv, attn);

    // 4) out = attn @ Wo^T       (5120 x 1024, K=1024)
    gemm_abt<<<dim3(DIM / 128, total / 128), 256, 0, stream>>>(
        attn, Wo, out, total, DIM, DIM);
}

// Round 6
// 1262.056 us; speedup vs baseline: 1.7292x; 1.7292x over previous
//
#include <hip/hip_runtime.h>
#include <math.h>

#define NH 16
#define HD 64
#define DIM 1024
#define QKV_DIM 3072
#define MAXLEN 2048

// hardcoded problem constants (fixed by reference setup)
__device__ __constant__ int g_cu[5]  = {0, 2048, 3584, 4608, 5120};
__device__ __constant__ int g_seq[4] = {2048, 1536, 1024, 512};

// ---------------------------------------------------------------------------
// GEMM: C[M][N] = A[M][K] * B[N][K]^T   (both A,B row-major, K-contiguous)
// 128x128 tile, BK=16, 256 threads, 8x8 per thread, fp32.
// ---------------------------------------------------------------------------
__global__ __launch_bounds__(256) void gemm_abt(const float* __restrict__ A,
                                                const float* __restrict__ B,
                                                float* __restrict__ C,
                                                int M, int N, int K) {
    constexpr int BM = 128, BN = 128, BK = 16;
    __shared__ float As[BK][BM + 4];
    __shared__ float Bs[BK][BN + 4];

    const int tid = threadIdx.x;
    const int bm = blockIdx.y * BM;
    const int bn = blockIdx.x * BN;
    const int ty = tid / 16;
    const int tx = tid % 16;

    float acc[8][8] = {};

    for (int k0 = 0; k0 < K; k0 += BK) {
#pragma unroll
        for (int it = 0; it < 2; ++it) {
            int item = tid + it * 256;
            int r = item >> 2;
            int c4 = item & 3;
            float4 v = *(const float4*)&A[(size_t)(bm + r) * K + k0 + c4 * 4];
            As[c4 * 4 + 0][r] = v.x;
            As[c4 * 4 + 1][r] = v.y;
            As[c4 * 4 + 2][r] = v.z;
            As[c4 * 4 + 3][r] = v.w;
        }
#pragma unroll
        for (int it = 0; it < 2; ++it) {
            int item = tid + it * 256;
            int r = item >> 2;
            int c4 = item & 3;
            float4 v = *(const float4*)&B[(size_t)(bn + r) * K + k0 + c4 * 4];
            Bs[c4 * 4 + 0][r] = v.x;
            Bs[c4 * 4 + 1][r] = v.y;
            Bs[c4 * 4 + 2][r] = v.z;
            Bs[c4 * 4 + 3][r] = v.w;
        }
        __syncthreads();

#pragma unroll
        for (int k = 0; k < BK; ++k) {
            float a[8], b[8];
            *(float4*)&a[0] = *(const float4*)&As[k][ty * 8 + 0];
            *(float4*)&a[4] = *(const float4*)&As[k][ty * 8 + 4];
            *(float4*)&b[0] = *(const float4*)&Bs[k][tx * 8 + 0];
            *(float4*)&b[4] = *(const float4*)&Bs[k][tx * 8 + 4];
#pragma unroll
            for (int i = 0; i < 8; ++i)
#pragma unroll
                for (int j = 0; j < 8; ++j) acc[i][j] = fmaf(a[i], b[j], acc[i][j]);
        }
        __syncthreads();
    }

#pragma unroll
    for (int i = 0; i < 8; ++i) {
#pragma unroll
        for (int j = 0; j < 8; j += 4) {
            float4 v = {acc[i][j], acc[i][j + 1], acc[i][j + 2], acc[i][j + 3]};
            *(float4*)&C[(size_t)(bm + ty * 8 + i) * N + bn + tx * 8 + j] = v;
        }
    }
}

// ---------------------------------------------------------------------------
// RoPE in place on q and k halves of the unpadded qkv buffer.
// ---------------------------------------------------------------------------
__global__ __launch_bounds__(256) void rope_kernel(float* __restrict__ qkv, int total) {
    int id = blockIdx.x * blockDim.x + threadIdx.x;
    int nitems = total * NH * 32;
    if (id >= nitems) return;
    int j = id & 31;
    int h = (id >> 5) & (NH - 1);
    int row = id >> 9;

    int b = 0;
    while (row >= g_cu[b + 1]) b++;
    int pos = row - g_cu[b];

    float inv_freq = powf(10000.0f, -(float)(2 * j) / 64.0f);
    float fr = (float)pos * inv_freq;
    float c = cosf(fr), s = sinf(fr);

    float* base = qkv + (size_t)row * QKV_DIM + h * HD;
#pragma unroll
    for (int part = 0; part < 2; ++part) {
        float* p = base + part * DIM;
        float x1 = p[j];
        float x2 = p[j + 32];
        p[j] = x1 * c - x2 * s;
        p[j + 32] = x2 * c + x1 * s;
    }
}

// ---------------------------------------------------------------------------
// Attention v4: GEMM-structured flash attention (fp32 VALU).
// Block = 256 threads (16x16 grid), one 64-query tile of one (batch,head).
// Per 64-key tile: QK^T via register outer product (thread owns a 4x4 score
// tile; per k-step 2 ds_read_b128 feed 16 FMAs — v2/v3 needed 8 reads per 32
// FMAs), shfl-reduce row softmax within 16-lane row groups, P written
// transposed to LDS, then PV via the same outer-product structure.
// Q/K/P stored transposed at stride 68 (16B-aligned, conflict-free: a-reads
// are 16-lane broadcasts, b-reads 2-way aliased = free). V row-major [64][64].
// Per-thread state ~70 VGPR -> no spill (the v1/v3 killer). Softmax in exp2
// domain (log2e folded into Q at staging). Padded keys (score 0, v 0)
// contribute (MAXLEN-L)*2^(-m) to the denominator only.
// ---------------------------------------------------------------------------
__global__ __launch_bounds__(256) void attn_kernel(const float* __restrict__ qkv,
                                                   float* __restrict__ attn) {
    __shared__ float Qt[64][68];
    __shared__ float Kt[64][68];
    __shared__ float Pt[64][68];
    __shared__ float Vs[64][64];

    // blockIdx.x in [0,80): per-batch 64-row tile counts {32,24,16,8}.
    const int tiles_pref[5] = {0, 32, 56, 72, 80};
    int t = blockIdx.x;
    int b = 0;
    while (t >= tiles_pref[b + 1]) b++;
    const int qstart = (t - tiles_pref[b]) * 64;
    const int h = blockIdx.y;
    const int L = g_seq[b];
    const int base = g_cu[b];
    const int tid = threadIdx.x;
    const int ty = tid >> 4;   // 0..15: row group (4 rows)
    const int tx = tid & 15;   // 0..15: col group (4 cols)
    const int tyo = ty * 4, txo = tx * 4;

    const float scale = 0.125f * 1.44269504088896f;  // 1/sqrt(64) * log2(e)

    // Stage Q transposed + scaled: Qt[k][r] = Q[r][k]*scale
#pragma unroll
    for (int it = 0; it < 4; ++it) {
        int item = tid + it * 256;
        int r = item >> 4, c4 = item & 15;
        const float* src = qkv + (size_t)(base + qstart + r) * QKV_DIM + h * HD + c4 * 4;
        float4 v = *(const float4*)src;
        Qt[c4 * 4 + 0][r] = v.x * scale;
        Qt[c4 * 4 + 1][r] = v.y * scale;
        Qt[c4 * 4 + 2][r] = v.z * scale;
        Qt[c4 * 4 + 3][r] = v.w * scale;
    }

    float o[4][4] = {};
    float m[4] = {-1e30f, -1e30f, -1e30f, -1e30f};
    float d[4] = {};

    for (int k0 = 0; k0 < L; k0 += 64) {
        __syncthreads();  // guards Qt (first iter) and Kt/Vs/Pt reuse
        // stage K transposed + V row-major
#pragma unroll
        for (int it = 0; it < 4; ++it) {
            int item = tid + it * 256;
            int r = item >> 4, c4 = item & 15;
            const float* src = qkv + (size_t)(base + k0 + r) * QKV_DIM + DIM + h * HD + c4 * 4;
            float4 kv = *(const float4*)src;
            Kt[c4 * 4 + 0][r] = kv.x;
            Kt[c4 * 4 + 1][r] = kv.y;
            Kt[c4 * 4 + 2][r] = kv.z;
            Kt[c4 * 4 + 3][r] = kv.w;
            *(float4*)&Vs[r][c4 * 4] = *(const float4*)(src + DIM);
        }
        __syncthreads();

        // QK^T outer product: s[i][j], rows tyo+i, cols txo+j
        float s[4][4] = {};
#pragma unroll 8
        for (int k = 0; k < 64; ++k) {
            float4 a = *(const float4*)&Qt[k][tyo];
            float4 bb = *(const float4*)&Kt[k][txo];
            s[0][0] = fmaf(a.x, bb.x, s[0][0]);
            s[0][1] = fmaf(a.x, bb.y, s[0][1]);
            s[0][2] = fmaf(a.x, bb.z, s[0][2]);
            s[0][3] = fmaf(a.x, bb.w, s[0][3]);
            s[1][0] = fmaf(a.y, bb.x, s[1][0]);
            s[1][1] = fmaf(a.y, bb.y, s[1][1]);
            s[1][2] = fmaf(a.y, bb.z, s[1][2]);
            s[1][3] = fmaf(a.y, bb.w, s[1][3]);
            s[2][0] = fmaf(a.z, bb.x, s[2][0]);
            s[2][1] = fmaf(a.z, bb.y, s[2][1]);
            s[2][2] = fmaf(a.z, bb.z, s[2][2]);
            s[2][3] = fmaf(a.z, bb.w, s[2][3]);
            s[3][0] = fmaf(a.w, bb.x, s[3][0]);
            s[3][1] = fmaf(a.w, bb.y, s[3][1]);
            s[3][2] = fmaf(a.w, bb.z, s[3][2]);
            s[3][3] = fmaf(a.w, bb.w, s[3][3]);
        }

        // online softmax per row (reduce across the 16-lane row group)
#pragma unroll
        for (int i = 0; i < 4; ++i) {
            float rmax = fmaxf(fmaxf(s[i][0], s[i][1]), fmaxf(s[i][2], s[i][3]));
            rmax = fmaxf(rmax, __shfl_xor(rmax, 1));
            rmax = fmaxf(rmax, __shfl_xor(rmax, 2));
            rmax = fmaxf(rmax, __shfl_xor(rmax, 4));
            rmax = fmaxf(rmax, __shfl_xor(rmax, 8));
            float mn = fmaxf(m[i], rmax);
            float corr = exp2f(m[i] - mn);
            m[i] = mn;
            float p0 = exp2f(s[i][0] - mn);
            float p1 = exp2f(s[i][1] - mn);
            float p2 = exp2f(s[i][2] - mn);
            float p3 = exp2f(s[i][3] - mn);
            float ps = (p0 + p1) + (p2 + p3);
            ps += __shfl_xor(ps, 1);
            ps += __shfl_xor(ps, 2);
            ps += __shfl_xor(ps, 4);
            ps += __shfl_xor(ps, 8);
            d[i] = d[i] * corr + ps;
            o[i][0] *= corr; o[i][1] *= corr; o[i][2] *= corr; o[i][3] *= corr;
            s[i][0] = p0; s[i][1] = p1; s[i][2] = p2; s[i][3] = p3;
        }

        // write P transposed: Pt[key][row]
#pragma unroll
        for (int j = 0; j < 4; ++j) {
            float4 pv = {s[0][j], s[1][j], s[2][j], s[3][j]};
            *(float4*)&Pt[txo + j][tyo] = pv;
        }
        __syncthreads();

        // PV outer product: o[i][j] += sum_kk P[row][kk] * V[kk][dim]
#pragma unroll 8
        for (int kk = 0; kk < 64; ++kk) {
            float4 a = *(const float4*)&Pt[kk][tyo];
            float4 bb = *(const float4*)&Vs[kk][txo];
            o[0][0] = fmaf(a.x, bb.x, o[0][0]);
            o[0][1] = fmaf(a.x, bb.y, o[0][1]);
            o[0][2] = fmaf(a.x, bb.z, o[0][2]);
            o[0][3] = fmaf(a.x, bb.w, o[0][3]);
            o[1][0] = fmaf(a.y, bb.x, o[1][0]);
            o[1][1] = fmaf(a.y, bb.y, o[1][1]);
            o[1][2] = fmaf(a.y, bb.z, o[1][2]);
            o[1][3] = fmaf(a.y, bb.w, o[1][3]);
            o[2][0] = fmaf(a.z, bb.x, o[2][0]);
            o[2][1] = fmaf(a.z, bb.y, o[2][1]);
            o[2][2] = fmaf(a.z, bb.z, o[2][2]);
            o[2][3] = fmaf(a.z, bb.w, o[2][3]);
            o[3][0] = fmaf(a.w, bb.x, o[3][0]);
            o[3][1] = fmaf(a.w, bb.y, o[3][1]);
            o[3][2] = fmaf(a.w, bb.z, o[3][2]);
            o[3][3] = fmaf(a.w, bb.w, o[3][3]);
        }
    }

    // padded keys: score 0 (in exp2-scaled domain too), v 0 -> denom only
    int npad = MAXLEN - L;
    if (npad) {
#pragma unroll
        for (int i = 0; i < 4; ++i) d[i] += (float)npad * exp2f(0.0f - m[i]);
    }

    // write output: rows qstart+tyo+i, dims h*64 + txo..+4
#pragma unroll
    for (int i = 0; i < 4; ++i) {
        float inv = 1.0f / d[i];
        float4 v = {o[i][0] * inv, o[i][1] * inv, o[i][2] * inv, o[i][3] * inv};
        *(float4*)&attn[(size_t)(base + qstart + tyo + i) * DIM + h * HD + txo] = v;
    }
}

// ---------------------------------------------------------------------------
extern "C" void kernel_launch(void* const* d_in, const int* in_sizes, int n_in,
                              void* d_out, int out_size, void* d_ws, size_t ws_size,
                              hipStream_t stream) {
    const float* hidden = (const float*)d_in[0];
    const float* Wqkv = (const float*)d_in[1];
    const float* Wo = (const float*)d_in[2];
    float* out = (float*)d_out;

    const int total = in_sizes[0] / DIM;  // 5120

    float* qkv = (float*)d_ws;                        // total * 3072
    float* attn = qkv + (size_t)total * QKV_DIM;      // total * 1024

    // 1) qkv = hidden @ Wqkv^T   (5120 x 3072, K=1024)
    gemm_abt<<<dim3(QKV_DIM / 128, total / 128), 256, 0, stream>>>(
        hidden, Wqkv, qkv, total, QKV_DIM, DIM);

    // 2) RoPE in place on q,k
    int nitems = total * NH * 32;
    rope_kernel<<<(nitems + 255) / 256, 256, 0, stream>>>(qkv, total);

    // 3) attention -> attn buffer
    attn_kernel<<<dim3(80, NH), 256, 0, stream>>>(qkv, attn);

    // 4) out = attn @ Wo^T       (5120 x 1024, K=1024)
    gemm_abt<<<dim3(DIM / 128, total / 128), 256, 0, stream>>>(
        attn, Wo, out, total, DIM, DIM);
}